// Round 3
// baseline (573.595 us; speedup 1.0000x reference)
//
#include <hip/hip_runtime.h>

#define NIMG 16
#define CI   128
#define CO   256
#define HH   128
#define WW   128
#define HP   130
#define WP   130

typedef short bf16x8 __attribute__((ext_vector_type(8)));
typedef float f32x4  __attribute__((ext_vector_type(4)));

typedef __attribute__((address_space(3))) unsigned int as3_u32;
typedef __attribute__((address_space(1))) const unsigned int as1_u32;

#define VMCNT(n) asm volatile("s_waitcnt vmcnt(" #n ")" ::: "memory")

__device__ __forceinline__ unsigned short f2bf(float f) {
    unsigned u = __builtin_bit_cast(unsigned, f);
    unsigned r = u + 0x7fffu + ((u >> 16) & 1u);   // RNE
    return (unsigned short)(r >> 16);
}

__device__ __forceinline__ void gload16(const unsigned short* g, void* lds) {
    // 16B per lane, HW writes lds_base + lane*16 (linear); source addr is per-lane.
    __builtin_amdgcn_global_load_lds((as1_u32*)g, (as3_u32*)lds, 16, 0, 0);
}

// ---------------------------------------------------------------------------
// Fused prep: bid < NIMG*HP -> x transform (NCHW f32 -> padded NHWC bf16),
// else -> weight transform (OIHW f32 -> wt[tap][co][ci] bf16 * kx[i]*kx[j]).
// x-part: pair-packed b32 LDS writes (XOR swizzle on c bits [2:1] keyed by
// (w>>3)&3), b128 reads + in-register word un-swizzle, coalesced 16B stores.
// ---------------------------------------------------------------------------
__global__ __launch_bounds__(256) void prep(const float* __restrict__ x,
                                            const float* __restrict__ wsrc,
                                            unsigned short* __restrict__ wt,
                                            unsigned short* __restrict__ xt) {
    int bid = blockIdx.x;
    int t = threadIdx.x;

    if (bid >= NIMG * HP) {                      // ---- weight part ----
        int idx = (bid - NIMG * HP) * 256 + t;   // (tap*256 + o)*128 + ci
        int ci   = idx & 127;
        int rest = idx >> 7;
        int o    = rest & 255;
        int tap  = rest >> 8;
        int i = tap / 3, j = tap - 3 * i;
        const float s0 = 0.7f;
        float si = (i == 1) ? 1.0f : s0;
        float sj = (j == 1) ? 1.0f : s0;
        wt[idx] = f2bf(wsrc[((o * 128 + ci) * 3 + i) * 3 + j] * si * sj);
        return;
    }

    // ---- x part ----
    int n = bid / 130, hp = bid - n * 130;
    size_t rowbase = (size_t)bid * WP * CI;      // elems at (n,hp,0,0)

    if (hp == 0 || hp == 129) {                  // zero border row
        int4 z = make_int4(0, 0, 0, 0);
        for (int c = t; c < (WP * CI * 2) / 16; c += 256)
            *(int4*)((char*)(xt + rowbase) + (size_t)c * 16) = z;
        return;
    }
    int h = hp - 1;

    __shared__ __align__(16) unsigned short ls[128][136];

#pragma unroll
    for (int k = 0; k < 8; ++k) {
        int idx = k * 256 + t;                   // 0..2047
        int c2 = idx >> 5;                       // channel pair 0..63
        int w4 = idx & 31;                       // float4 chunk along w
        const float* p = &x[(((size_t)n * CI + 2 * c2) * HH + h) * WW + w4 * 4];
        float4 a = *(const float4*)p;
        float4 b = *(const float4*)(p + (size_t)HH * WW);
        int cb = (2 * c2) ^ (((w4 >> 1) & 3) << 1);   // XOR on c bits [2:1]
        *(unsigned*)&ls[w4 * 4 + 0][cb] = (unsigned)f2bf(a.x) | ((unsigned)f2bf(b.x) << 16);
        *(unsigned*)&ls[w4 * 4 + 1][cb] = (unsigned)f2bf(a.y) | ((unsigned)f2bf(b.y) << 16);
        *(unsigned*)&ls[w4 * 4 + 2][cb] = (unsigned)f2bf(a.z) | ((unsigned)f2bf(b.z) << 16);
        *(unsigned*)&ls[w4 * 4 + 3][cb] = (unsigned)f2bf(a.w) | ((unsigned)f2bf(b.w) << 16);
    }
    // w-border zero chunks (independent of LDS)
    if (t < 32) {
        int side = t >> 4, part = t & 15;
        size_t o = rowbase + (side ? (size_t)129 * CI : 0) + part * 8;
        *(int4*)(xt + o) = make_int4(0, 0, 0, 0);
    }
    __syncthreads();

    size_t obase = rowbase + CI;                 // wp = 1
    for (int it = 0; it < 8; ++it) {
        int chunk = it * 256 + t;                // 0..2047
        int ww = chunk >> 4, cp = chunk & 15;
        int4 v = *(const int4*)&ls[ww][cp * 8];
        int s = (ww >> 3) & 3;
        int4 o = v;
        if (s & 1) o = make_int4(o.y, o.x, o.w, o.z);
        if (s & 2) o = make_int4(o.z, o.w, o.x, o.y);
        *(int4*)((char*)(xt + obase) + (size_t)chunk * 16) = o;
    }
}

// ---------------------------------------------------------------------------
// Main: implicit-GEMM conv, 128 px x 128 co per block, 4 waves, acc 4x4.
// 36 steps (kc 0..3 x tap 0..8). Weights triple-buffered in LDS, staged
// TWO steps ahead with counted s_waitcnt vmcnt(2) (never drain-0 in steady
// state; T4). xs halo single-buffered, re-staged at each kc boundary with
// one explicit issue->vmcnt(2)->barrier bubble. s_setprio around MFMA (T5).
// XOR slot swizzles on xs and ws keep ds_read_b128 conflict-free.
// ---------------------------------------------------------------------------
__global__ __launch_bounds__(256, 3) void conv_mfma(const unsigned short* __restrict__ xt,
                                                    const unsigned short* __restrict__ wt,
                                                    const float* __restrict__ bias,
                                                    float* __restrict__ out) {
    // bijective XCD swizzle: nwg=4096, 512 contiguous work items per XCD
    int bid0 = blockIdx.x;
    int wk  = (bid0 & 7) * 512 + (bid0 >> 3);
    int bn  = wk & 1;             // co half
    int bm  = wk >> 1;            // (n,h)
    int n = bm >> 7, h = bm & 127;
    int tid  = threadIdx.x;
    int lane = tid & 63, wv = tid >> 6;
    int mw = wv & 1, nw = wv >> 1;
    int lr = lane & 15;
    int lq = lane >> 4;

    // LDS: ws[3] @0 (3*8192=24576), xs @24576 (28672) => 53248 (3 blocks/CU)
    __shared__ __align__(1024) char smem[53248];
    char* xsb = smem + 24576;

    f32x4 acc[4][4];
    const f32x4 zero = {0.0f, 0.0f, 0.0f, 0.0f};
    for (int mi = 0; mi < 4; ++mi)
        for (int ni = 0; ni < 4; ++ni) acc[mi][ni] = zero;

    int pm[4];                    // A pixel index per mi
    for (int mi = 0; mi < 4; ++mi) pm[mi] = mw * 64 + mi * 16 + lr;
    // B read offset (byte, within ws buffer, +ni*1024 per frag)
    int boff = (nw * 64 + lr) * 64 + ((lq ^ ((lr >> 1) & 3)) << 4);

    // ws staging source invariants: chunk c = (co<<2)|slot, q = slot^((co>>1)&3)
    int wsrc_off[2];
#pragma unroll
    for (int i = 0; i < 2; ++i) {
        int c = wv * 128 + i * 64 + lane;          // 0..511
        int co = c >> 2, slot = c & 3;
        int q = slot ^ ((co >> 1) & 3);
        wsrc_off[i] = (bn * 128 + co) * CI + q * 8;
    }

    // xs staging source invariants: chunk c = (p<<2)|slot, q = slot^((p>>1)&3)
    int goffs[7];
    int nbase = n * (HP * WP * CI);
#pragma unroll
    for (int i = 0; i < 7; ++i) {
        int c = wv * 448 + i * 64 + lane;
        int pp = (c < 1560) ? (c >> 2) : 0;       // clamp tail chunks in-bounds
        int slot = c & 3;
        int q = slot ^ ((pp >> 1) & 3);
        int dh = (pp * 505) >> 16;                // pp / 130 for pp < 390
        int wp = pp - dh * 130;
        goffs[i] = nbase + ((h + dh) * WP + wp) * CI + q * 8;
    }

    auto stage_ws = [&](int buf, int kc_, int tap_) {
        const unsigned short* src = wt + (size_t)tap_ * CO * CI + kc_ * 32;
#pragma unroll
        for (int i = 0; i < 2; ++i)
            gload16(src + wsrc_off[i], smem + buf * 8192 + wv * 2048 + i * 1024);
    };
    auto stage_xs = [&](int kc_) {
#pragma unroll
        for (int i = 0; i < 7; ++i)
            gload16(xt + goffs[i] + kc_ * 32, xsb + wv * 7168 + i * 1024);
    };

    // prologue: xs(0) first (oldest in FIFO), then ws(0), ws(1)
    stage_xs(0);
    stage_ws(0, 0, 0);
    stage_ws(1, 0, 1);

#pragma unroll 1
    for (int kc = 0; kc < 4; ++kc) {
#pragma unroll
        for (int tap = 0; tap < 9; ++tap) {
            // counted wait: retire ws(t) (and xs/ws backlog), keep 2 newest in flight
            if (tap == 8) {
                if (kc == 3) { VMCNT(0); } else { VMCNT(2); }
            } else {
                VMCNT(2);
            }
            __builtin_amdgcn_s_barrier();
            __builtin_amdgcn_sched_barrier(0);

            if (tap == 0) {
                if (kc > 0) stage_xs(kc);          // 7 loads (oldest)
                stage_ws(2, kc, 2);                // ws(9kc+2) -> buf 2
                __builtin_amdgcn_sched_barrier(0);
                if (kc > 0) {                      // drain xs, publish, keep ws(9kc+2) in flight
                    VMCNT(2);
                    __builtin_amdgcn_s_barrier();
                    __builtin_amdgcn_sched_barrier(0);
                }
            } else if (tap <= 6) {
                stage_ws((tap + 2) % 3, kc, tap + 2);
                __builtin_amdgcn_sched_barrier(0);
            } else {                               // tap 7/8 stage next kc's ws 0/1
                if (kc < 3) stage_ws(tap - 7, kc + 1, tap - 7);
                __builtin_amdgcn_sched_barrier(0);
            }

            const char* wsb = smem + (tap % 3) * 8192;
            int di = tap / 3, dj = tap - 3 * di;
            int pd = di * 130 + dj;
            bf16x8 a[4], b[4];
#pragma unroll
            for (int mi = 0; mi < 4; ++mi) {
                int p = pd + pm[mi];
                int sw = (p >> 1) & 3;
                a[mi] = *(const bf16x8*)(xsb + p * 64 + ((lq ^ sw) << 4));
            }
#pragma unroll
            for (int ni = 0; ni < 4; ++ni)
                b[ni] = *(const bf16x8*)(wsb + ni * 1024 + boff);
            __builtin_amdgcn_s_setprio(1);
#pragma unroll
            for (int mi = 0; mi < 4; ++mi)
#pragma unroll
                for (int ni = 0; ni < 4; ++ni)
                    acc[mi][ni] = __builtin_amdgcn_mfma_f32_16x16x32_bf16(
                        a[mi], b[ni], acc[mi][ni], 0, 0, 0);
            __builtin_amdgcn_s_setprio(0);
        }
    }

    // epilogue: LDS transpose -> coalesced NCHW stores (+bias). es aliases smem.
    float (*es)[16][68] = (float (*)[16][68])smem;
    for (int ni = 0; ni < 4; ++ni) {
        __syncthreads();
        for (int mi = 0; mi < 4; ++mi) {
            *(float4*)&es[wv][lr][mi * 16 + lq * 4] = *(const float4*)&acc[mi][ni];
        }
        __syncthreads();
        int row = lane >> 2;
        int cp  = lane & 3;
        int co = bn * 128 + nw * 64 + ni * 16 + row;
        float bco = bias[co];
        size_t obase = (((size_t)n * CO + co) * HH + h) * WW + mw * 64 + cp * 16;
#pragma unroll
        for (int q = 0; q < 4; ++q) {
            float4 tv = *(const float4*)&es[wv][row][cp * 16 + q * 4];
            tv.x += bco; tv.y += bco; tv.z += bco; tv.w += bco;
            *(float4*)(out + obase + q * 4) = tv;
        }
    }
}

// ---------------------------------------------------------------------------
// Fallback: direct fp32 conv (only if workspace too small)
// ---------------------------------------------------------------------------
__global__ void conv_direct(const float* __restrict__ x, const float* __restrict__ wsrc,
                            const float* __restrict__ bias, float* __restrict__ out) {
    int b = blockIdx.x;           // ((n*256+o)*128 + h)
    int w = threadIdx.x;
    int h = b & 127;
    int rest = b >> 7;
    int o = rest & 255, n = rest >> 8;
    const float s[3] = {0.7f, 1.0f, 0.7f};
    float acc = bias[o];
    for (int ci = 0; ci < 128; ++ci) {
        const float* xp = x + ((size_t)n * CI + ci) * HH * WW;
        const float* wp = wsrc + ((size_t)o * CI + ci) * 9;
        for (int i = 0; i < 3; ++i) {
            int r = h + i - 1;
            if ((unsigned)r >= 128u) continue;
            for (int j = 0; j < 3; ++j) {
                int c = w + j - 1;
                if ((unsigned)c >= 128u) continue;
                acc += xp[r * 128 + c] * wp[i * 3 + j] * s[i] * s[j];
            }
        }
    }
    out[(size_t)b * 128 + w] = acc;
}

extern "C" void kernel_launch(void* const* d_in, const int* in_sizes, int n_in,
                              void* d_out, int out_size, void* d_ws, size_t ws_size,
                              hipStream_t stream) {
    const float* x    = (const float*)d_in[0];
    const float* wsrc = (const float*)d_in[1];
    const float* bias = (const float*)d_in[2];
    float* out = (float*)d_out;

    const size_t wt_bytes = (size_t)9 * CO * CI * 2;              // 589,824
    const size_t xt_bytes = (size_t)NIMG * HP * WP * CI * 2;      // 69,222,400
    if (ws_size < wt_bytes + xt_bytes) {
        conv_direct<<<NIMG * CO * HH, 128, 0, stream>>>(x, wsrc, bias, out);
        return;
    }
    unsigned short* wt = (unsigned short*)d_ws;
    unsigned short* xt = (unsigned short*)((char*)d_ws + wt_bytes);

    prep<<<NIMG * HP + (9 * CO * CI) / 256, 256, 0, stream>>>(x, wsrc, wt, xt);
    conv_mfma<<<NIMG * HH * 2, 256, 0, stream>>>(xt, wt, bias, out);
}

// Round 4
// 549.535 us; speedup vs baseline: 1.0438x; 1.0438x over previous
//
#include <hip/hip_runtime.h>

#define NIMG 16
#define CI   128
#define CO   256
#define HH   128
#define WW   128

typedef short bf16x8 __attribute__((ext_vector_type(8)));
typedef float f32x4  __attribute__((ext_vector_type(4)));

typedef __attribute__((address_space(3))) unsigned int as3_u32;
typedef __attribute__((address_space(1))) const unsigned int as1_u32;

#define VMCNT0   asm volatile("s_waitcnt vmcnt(0)" ::: "memory")
#define LGKMCNT0 asm volatile("s_waitcnt lgkmcnt(0)" ::: "memory")

__device__ __forceinline__ unsigned short f2bf(float f) {
    unsigned u = __builtin_bit_cast(unsigned, f);
    unsigned r = u + 0x7fffu + ((u >> 16) & 1u);   // RNE
    return (unsigned short)(r >> 16);
}

__device__ __forceinline__ void gload16(const unsigned short* g, void* lds) {
    // 16B per lane, HW writes lds_base + lane*16 (linear); source addr is per-lane.
    __builtin_amdgcn_global_load_lds((as1_u32*)g, (as3_u32*)lds, 16, 0, 0);
}

// ---------------------------------------------------------------------------
// Prep: weights OIHW fp32 -> wt[tap][co][ci] bf16, scaled by kx[i]*kx[j].
// (x is consumed directly by conv_mfma now — no x intermediate.)
// ---------------------------------------------------------------------------
__global__ void xform_w(const float* __restrict__ wsrc, unsigned short* __restrict__ wt) {
    int idx = blockIdx.x * 256 + threadIdx.x;       // (tap*256 + o)*128 + ci
    int ci   = idx & 127;
    int rest = idx >> 7;
    int o    = rest & 255;
    int tap  = rest >> 8;
    int i = tap / 3, j = tap - 3 * i;
    const float s0 = 0.7f;
    float si = (i == 1) ? 1.0f : s0;
    float sj = (j == 1) ? 1.0f : s0;
    wt[idx] = f2bf(wsrc[((o * 128 + ci) * 3 + i) * 3 + j] * si * sj);
}

// ---------------------------------------------------------------------------
// Main: implicit-GEMM conv, 128 px x 128 co per block, 4 waves, acc 4x4.
// R2's proven 2-phase ws pipeline (double-buffered LDS weights, vmcnt(0) +
// barrier per tap-step). NEW: xs halo (3x130 px x 32 ci bf16) is built
// in-kernel at each kc boundary straight from x (fp32 NCHW): 12 coalesced
// float4 loads/thread -> f2bf pair-pack -> b32 writes into the same
// slot-XOR-swizzled layout the (proven 0-conflict) A-read path expects.
// Eliminates the xt workspace pass entirely.
// ---------------------------------------------------------------------------
__global__ __launch_bounds__(256, 2) void conv_mfma(const float* __restrict__ x,
                                                    const unsigned short* __restrict__ wt,
                                                    const float* __restrict__ bias,
                                                    float* __restrict__ out) {
    // bijective XCD swizzle: nwg=4096, 512 contiguous work items per XCD
    int bid0 = blockIdx.x;
    int wk  = (bid0 & 7) * 512 + (bid0 >> 3);
    int bn  = wk & 1;             // co half
    int bm  = wk >> 1;            // (n,h)
    int n = bm >> 7, h = bm & 127;
    int tid  = threadIdx.x;
    int lane = tid & 63, wv = tid >> 6;
    int mw = wv & 1, nw = wv >> 1;
    int lr = lane & 15;
    int lq = lane >> 4;

    // LDS: ws[2] @0 (2*8192=16384), xs @16384 (390 px * 64B = 24960) => 41344
    __shared__ __align__(1024) char smem[41344];
    char* xsb = smem + 16384;

    f32x4 acc[4][4];
    const f32x4 zero = {0.0f, 0.0f, 0.0f, 0.0f};
    for (int mi = 0; mi < 4; ++mi)
        for (int ni = 0; ni < 4; ++ni) acc[mi][ni] = zero;

    int pm[4];                    // A pixel index per mi
    for (int mi = 0; mi < 4; ++mi) pm[mi] = mw * 64 + mi * 16 + lr;
    // B read offset (byte, within ws buffer, +ni*1024 per frag)
    int boff = (nw * 64 + lr) * 64 + ((lq ^ ((lr >> 1) & 3)) << 4);

    // ws staging source invariants: chunk c = (co<<2)|slot, q = slot^((co>>1)&3)
    int wsrc_off[2];
#pragma unroll
    for (int i = 0; i < 2; ++i) {
        int c = wv * 128 + i * 64 + lane;          // 0..511
        int co = c >> 2, slot = c & 3;
        int q = slot ^ ((co >> 1) & 3);
        wsrc_off[i] = (bn * 128 + co) * CI + q * 8;
    }

    auto stage_ws = [&](int par, int kc_, int tap_) {
        const unsigned short* src = wt + (size_t)tap_ * CO * CI + kc_ * 32;
#pragma unroll
        for (int i = 0; i < 2; ++i)
            gload16(src + wsrc_off[i], smem + par * 8192 + wv * 2048 + i * 1024);
    };

    // ---- in-kernel x staging: load 3 rows x 32 ci (kc chunk), transpose to
    //      xs[px][ci] bf16 with the slot-XOR swizzle the A-reads expect.
    int w4  = tid & 31;           // float4 chunk along w (lanes 0..31 coalesced)
    int cp0 = tid >> 5;           // ci-pair subgroup 0..7
    auto write_full_x = [&](int kcn) {
        float4 xa[6], xb[6];
#pragma unroll
        for (int it = 0; it < 6; ++it) {
            int r0 = h + (it >> 1) - 1;            // block-uniform validity
            int cp = cp0 | ((it & 1) << 3);        // ci pair 0..15
            int ci = kcn * 32 + 2 * cp;
            if ((unsigned)r0 < 128u) {
                const float* p = x + ((size_t)(n * CI + ci) * HH + r0) * WW + 4 * w4;
                xa[it] = *(const float4*)p;
                xb[it] = *(const float4*)(p + (size_t)HH * WW);
            } else {
                xa[it] = make_float4(0.f, 0.f, 0.f, 0.f);
                xb[it] = make_float4(0.f, 0.f, 0.f, 0.f);
            }
        }
#pragma unroll
        for (int it = 0; it < 6; ++it) {
            int cp = cp0 | ((it & 1) << 3);
            int slot = cp >> 2, word = cp & 3;
            int pxb = (it >> 1) * 130 + 1 + 4 * w4;
            float fx[4] = {xa[it].x, xa[it].y, xa[it].z, xa[it].w};
            float fy[4] = {xb[it].x, xb[it].y, xb[it].z, xb[it].w};
#pragma unroll
            for (int j = 0; j < 4; ++j) {
                int px = pxb + j;
                unsigned pv = (unsigned)f2bf(fx[j]) | ((unsigned)f2bf(fy[j]) << 16);
                int ss = slot ^ ((px >> 1) & 3);
                *(unsigned*)(xsb + px * 64 + ss * 16 + word * 4) = pv;
            }
        }
    };

    // prologue: ws(0,0) in flight while we build xs(0); zero w-halo px once
    stage_ws(0, 0, 0);
    write_full_x(0);
    if (tid < 96) {               // px in {0,129} per row: 6 px * 16 words
        int b = tid >> 4;
        int px = (b >> 1) * 130 + ((b & 1) ? 129 : 0);
        int cpz = tid & 15;
        int ss = (cpz >> 2) ^ ((px >> 1) & 3);
        *(unsigned*)(xsb + px * 64 + ss * 16 + (cpz & 3) * 4) = 0u;
    }
    LGKMCNT0;
    __builtin_amdgcn_sched_barrier(0);

#pragma unroll 1
    for (int kc = 0; kc < 4; ++kc) {
#pragma unroll
        for (int tap = 0; tap < 9; ++tap) {
            VMCNT0;
            __builtin_amdgcn_s_barrier();
            __builtin_amdgcn_sched_barrier(0);
            if (tap < 8) stage_ws((kc + tap + 1) & 1, kc, tap + 1);
            else if (kc < 3) stage_ws((kc + 1) & 1, kc + 1, 0);
            __builtin_amdgcn_sched_barrier(0);

            const char* wsb = smem + ((kc + tap) & 1) * 8192;
            int di = tap / 3, dj = tap - 3 * di;
            int pd = di * 130 + dj;
            bf16x8 a[4], b[4];
#pragma unroll
            for (int mi = 0; mi < 4; ++mi) {
                int p = pd + pm[mi];
                int sw = (p >> 1) & 3;
                a[mi] = *(const bf16x8*)(xsb + p * 64 + ((lq ^ sw) << 4));
            }
#pragma unroll
            for (int ni = 0; ni < 4; ++ni)
                b[ni] = *(const bf16x8*)(wsb + ni * 1024 + boff);
#pragma unroll
            for (int mi = 0; mi < 4; ++mi)
#pragma unroll
                for (int ni = 0; ni < 4; ++ni)
                    acc[mi][ni] = __builtin_amdgcn_mfma_f32_16x16x32_bf16(
                        a[mi], b[ni], acc[mi][ni], 0, 0, 0);

            if (tap == 8 && kc < 3) {
                // rebuild xs for kc+1 (ws(kc+1,0) load stays in flight)
                __builtin_amdgcn_s_barrier();       // all waves done reading xs(kc)
                __builtin_amdgcn_sched_barrier(0);
                write_full_x(kc + 1);
                LGKMCNT0;
                __builtin_amdgcn_sched_barrier(0);
                __builtin_amdgcn_s_barrier();       // publish xs(kc+1)
            }
        }
    }

    // epilogue: LDS transpose -> coalesced NCHW stores (+bias). es aliases smem.
    float (*es)[16][68] = (float (*)[16][68])smem;
    for (int ni = 0; ni < 4; ++ni) {
        __syncthreads();
        for (int mi = 0; mi < 4; ++mi) {
            *(float4*)&es[wv][lr][mi * 16 + lq * 4] = *(const float4*)&acc[mi][ni];
        }
        __syncthreads();
        int row = lane >> 2;
        int cp  = lane & 3;
        int co = bn * 128 + nw * 64 + ni * 16 + row;
        float bco = bias[co];
        size_t obase = (((size_t)n * CO + co) * HH + h) * WW + mw * 64 + cp * 16;
#pragma unroll
        for (int q = 0; q < 4; ++q) {
            float4 tv = *(const float4*)&es[wv][row][cp * 16 + q * 4];
            tv.x += bco; tv.y += bco; tv.z += bco; tv.w += bco;
            *(float4*)(out + obase + q * 4) = tv;
        }
    }
}

// ---------------------------------------------------------------------------
// Fallback: direct fp32 conv (only if workspace too small)
// ---------------------------------------------------------------------------
__global__ void conv_direct(const float* __restrict__ x, const float* __restrict__ wsrc,
                            const float* __restrict__ bias, float* __restrict__ out) {
    int b = blockIdx.x;           // ((n*256+o)*128 + h)
    int w = threadIdx.x;
    int h = b & 127;
    int rest = b >> 7;
    int o = rest & 255, n = rest >> 8;
    const float s[3] = {0.7f, 1.0f, 0.7f};
    float acc = bias[o];
    for (int ci = 0; ci < 128; ++ci) {
        const float* xp = x + ((size_t)n * CI + ci) * HH * WW;
        const float* wp = wsrc + ((size_t)o * CI + ci) * 9;
        for (int i = 0; i < 3; ++i) {
            int r = h + i - 1;
            if ((unsigned)r >= 128u) continue;
            for (int j = 0; j < 3; ++j) {
                int c = w + j - 1;
                if ((unsigned)c >= 128u) continue;
                acc += xp[r * 128 + c] * wp[i * 3 + j] * s[i] * s[j];
            }
        }
    }
    out[(size_t)b * 128 + w] = acc;
}

extern "C" void kernel_launch(void* const* d_in, const int* in_sizes, int n_in,
                              void* d_out, int out_size, void* d_ws, size_t ws_size,
                              hipStream_t stream) {
    const float* x    = (const float*)d_in[0];
    const float* wsrc = (const float*)d_in[1];
    const float* bias = (const float*)d_in[2];
    float* out = (float*)d_out;

    const size_t wt_bytes = (size_t)9 * CO * CI * 2;              // 589,824
    if (ws_size < wt_bytes) {
        conv_direct<<<NIMG * CO * HH, 128, 0, stream>>>(x, wsrc, bias, out);
        return;
    }
    unsigned short* wt = (unsigned short*)d_ws;

    xform_w<<<(9 * CO * CI) / 256, 256, 0, stream>>>(wsrc, wt);
    conv_mfma<<<NIMG * HH * 2, 256, 0, stream>>>(x, wt, bias, out);
}